// Round 6
// baseline (112.255 us; speedup 1.0000x reference)
//
#include <hip/hip_runtime.h>
#include <stdint.h>

typedef __bf16 bf16;
typedef bf16 bf16x8 __attribute__((ext_vector_type(8)));
typedef float floatx4 __attribute__((ext_vector_type(4)));

#define INV_T     2.0f                      // 1 / TEMPERATURE
#define SQRT_K    1.6986436206f             // sqrt(INV_T * log2(e))
#define INV_K     0.34657359028f            // ln(2)/2 = 1/(INV_T*log2(e))
#define GLOBAL_AS __attribute__((address_space(1)))
#define LDS_AS    __attribute__((address_space(3)))

// rep2 layout (16B chunks): chunk(r, ch) = (r>>6)*1024 + ch*64 + (r&63),
// ch = k>>3. MFMA A/B fragment loads and tile staging are fully coalesced,
// LDS fragment reads structurally conflict-free.

// R14 = MEASUREMENT ROUND: exact R10 champion source (87.2 us), but sim is
// launched TWICE (idempotent: rowsumP/pos are pure functions of rep2, and
// the stream orders the two dispatches). total - 87.2 = one true sim
// dispatch + ~2us launch. This discriminates "sim is ~35us and stalled"
// from "sim is ~10us and ~25us is launch/gap overhead" -- two optimization
// theories (R10' barrier-drain, R13 staging/occupancy) both failed on the
// unvalidated premise, and the fills crowd sim out of the top-5 so it has
// never been directly measured without confounds.

// ---------------------------------------------------------------------------
// Kernel 1: L2-normalize rows, scale by SQRT_K, write bf16 rep2 (swizzled).
// ---------------------------------------------------------------------------
__global__ __launch_bounds__(256) void nrm_kernel(const float* __restrict__ p1,
                                                  const float* __restrict__ p2,
                                                  uint32_t* __restrict__ rep2,
                                                  float* __restrict__ out) {
    int gt   = blockIdx.x * 256 + threadIdx.x;
    int row  = gt >> 6;
    int lane = gt & 63;
    const float* srcRow = (row < 4096) ? (p1 + (size_t)row * 128)
                                       : (p2 + (size_t)(row - 4096) * 128);
    float2 v = ((const float2*)srcRow)[lane];
    float ss = v.x * v.x + v.y * v.y;
#pragma unroll
    for (int s = 1; s < 64; s <<= 1) ss += __shfl_xor(ss, s, 64);
    float inv = SQRT_K / fmaxf(sqrtf(ss), 1e-12f);
    union { bf16 h[2]; uint32_t u; } pk;
    pk.h[0] = (bf16)(v.x * inv);
    pk.h[1] = (bf16)(v.y * inv);
    int chunk = (row >> 6) * 1024 + (lane >> 2) * 64 + (row & 63);
    rep2[chunk * 4 + (lane & 3)] = pk.u;
    if (gt == 0) *out = 0.0f;
}

// ---------------------------------------------------------------------------
// Kernel 2: SYMMETRIC rowsum partials + positive-pair dot. (R10 structure:
// whole 64KB B panel staged once via global_load_lds, one drain barrier,
// 16 barrier-free subtiles.)
//
// REGISTER-BUDGET HISTORY (don't re-tighten):
//   (256,4): 128-reg cap -> aF spills, 66 MB scratch, 85 us  (R7)
//   (256,3): 170-reg cap -> still spills (VGPR=84, 36 MB, 43 us)  (R8)
//   (256,2): 256-reg cap -> live set (~130) fits, no spill.
// ---------------------------------------------------------------------------
__global__ __launch_bounds__(256, 2) void sim_kernel(const uint4* __restrict__ rep2,
                                                     float* __restrict__ rowsumP,
                                                     float* __restrict__ pos) {
    __shared__ uint4 lB[4096];          // 64 KB: full 256-col x 128-k B panel
    __shared__ float colPart[4][256];   // 4 KB cross-wave colsum combine

    const int cb = blockIdx.x;     // col block: cols [cb*256, +256)
    const int rb = blockIdx.y;     // row block: rows [rb*256, +256)
    if (cb < rb) return;           // symmetry: upper triangle only

    const int tid  = threadIdx.x;
    const int w    = tid >> 6;
    const int lane = tid & 63;
    const int quad = lane >> 4;
    const int lcol = lane & 15;

    // Stage the WHOLE B panel in one shot: rep2[cb*4096 .. +4096) uint4s.
    {
        const uint4* src = rep2 + (size_t)cb * 4096;
#pragma unroll
        for (int jj = 0; jj < 16; jj++)
            __builtin_amdgcn_global_load_lds(
                (const GLOBAL_AS uint32_t*)(src + jj * 256 + tid),
                (LDS_AS uint32_t*)&lB[jj * 256 + tid], 16, 0, 0);
    }

    const int wbase = rb * 256 + w * 64;       // wave's rows (64-aligned)
    const int pbase = (wbase + 4096) & 8191;   // partner 64-col window

    // A fragments: rows wbase+mi*16+lcol, k = ks*32+quad*8..+7
    bf16x8 aF[4][4];
    const uint4* aG = rep2 + (size_t)(wbase >> 6) * 1024;
#pragma unroll
    for (int mi = 0; mi < 4; mi++)
#pragma unroll
        for (int ks = 0; ks < 4; ks++)
            aF[mi][ks] = *(const bf16x8*)&aG[(ks * 4 + quad) * 64 + mi * 16 + lcol];

    float rs[16];
#pragma unroll
    for (int i = 0; i < 16; i++) rs[i] = 0.0f;

    __syncthreads();   // one drain: panel in LDS, aF in regs

    // 16 subtiles, no barriers anywhere inside.
#pragma unroll
    for (int t = 0; t < 4; t++) {
#pragma unroll
        for (int so = 0; so < 4; so++) {
            bf16x8 bF[4];
#pragma unroll
            for (int ks = 0; ks < 4; ks++)
                bF[ks] = *(const bf16x8*)&lB[t * 1024 + (ks * 4 + quad) * 64 + so * 16 + lcol];

            floatx4 acc[4];
            const floatx4 zf = {0.0f, 0.0f, 0.0f, 0.0f};
#pragma unroll
            for (int mi = 0; mi < 4; mi++) acc[mi] = zf;
#pragma unroll
            for (int ks = 0; ks < 4; ks++)
#pragma unroll
                for (int mi = 0; mi < 4; mi++)
                    acc[mi] = __builtin_amdgcn_mfma_f32_16x16x32_bf16(
                        aF[mi][ks], bF[ks], acc[mi], 0, 0, 0);

            const int c0s  = cb * 256 + t * 64 + so * 16;
            const int gcol = c0s + lcol;
            const bool diagS = ((c0s & ~63) == wbase);   // => rb==cb && t==w
            const bool partS = ((c0s & ~63) == pbase);   // => cb==rb+16 && t==w
            float cs = 0.0f;                             // colsum partial
            if (diagS | partS) {
#pragma unroll
                for (int mi = 0; mi < 4; mi++)
#pragma unroll
                    for (int r = 0; r < 4; r++) {
                        int grow = wbase + mi * 16 + quad * 4 + r;
                        float s = acc[mi][r];
                        if (partS && gcol == grow + 4096) {   // rb<16 here
                            float d = s * INV_K;              // raw dot
                            pos[grow] = d;
                            pos[grow + 4096] = d;
                        }
                        float e = __builtin_amdgcn_exp2f(s);
                        if (diagS && grow == gcol) e = 0.0f;  // mask j == i
                        rs[mi * 4 + r] += e;
                        cs += e;
                    }
            } else {
#pragma unroll
                for (int mi = 0; mi < 4; mi++)
#pragma unroll
                    for (int r = 0; r < 4; r++) {
                        float e = __builtin_amdgcn_exp2f(acc[mi][r]);
                        rs[mi * 4 + r] += e;
                        cs += e;
                    }
            }
            // colsum over the wave's 64 rows: reduce across quads
            cs += __shfl_xor(cs, 16, 64);
            cs += __shfl_xor(cs, 32, 64);
            if (quad == 0) colPart[w][t * 64 + so * 16 + lcol] = cs;
        }
    }

    // row partials: reduce rs across lane bits 0-3 (16 cols per quad)
#pragma unroll
    for (int s = 1; s < 16; s <<= 1)
#pragma unroll
        for (int k = 0; k < 16; k++) rs[k] += __shfl_xor(rs[k], s, 64);

    if (lcol == 0) {
#pragma unroll
        for (int k = 0; k < 16; k++) {
            int grow = wbase + (k >> 2) * 16 + quad * 4 + (k & 3);
            rowsumP[(size_t)grow * 32 + cb] = rs[k];   // slot cb
        }
    }

    __syncthreads();   // colPart visibility for the cross-wave combine

    // col partials -> mirror rows' slot rb (skip self-tile)
    if (rb != cb) {
        float c = colPart[0][tid] + colPart[1][tid] + colPart[2][tid] + colPart[3][tid];
        rowsumP[(size_t)(cb * 256 + tid) * 32 + rb] = c;
    }
}

// ---------------------------------------------------------------------------
// Kernel 3: loss = (1/8192) * sum_i [ log(sum_c rowsumP[i][c]) - 2*pos_i ]
// ---------------------------------------------------------------------------
__global__ __launch_bounds__(128) void fin_kernel(const float* __restrict__ rowsumP,
                                                  const float* __restrict__ pos,
                                                  float* __restrict__ out) {
    int row = blockIdx.x * 128 + threadIdx.x;
    const floatx4* rp = (const floatx4*)(rowsumP + (size_t)row * 32);
    float d = 0.0f;
#pragma unroll
    for (int j = 0; j < 8; j++) {
        floatx4 q = rp[j];
        d += (q[0] + q[1]) + (q[2] + q[3]);
    }
    float v = logf(d) - pos[row] * INV_T;
#pragma unroll
    for (int s = 1; s < 64; s <<= 1) v += __shfl_xor(v, s, 64);
    __shared__ float red[2];
    if ((threadIdx.x & 63) == 0) red[threadIdx.x >> 6] = v;
    __syncthreads();
    if (threadIdx.x == 0)
        atomicAdd(out, (red[0] + red[1]) * (1.0f / 8192.0f));
}

extern "C" void kernel_launch(void* const* d_in, const int* in_sizes, int n_in,
                              void* d_out, int out_size, void* d_ws, size_t ws_size,
                              hipStream_t stream) {
    const float* p1 = (const float*)d_in[0];
    const float* p2 = (const float*)d_in[1];
    float* out = (float*)d_out;

    char* ws       = (char*)d_ws;
    uint32_t* rep2 = (uint32_t*)ws;                             // 2 MB
    float* rowsumP = (float*)(ws + (2u << 20));                 // 1 MB
    float* pos     = (float*)(ws + (3u << 20));                 // 32 KB

    nrm_kernel<<<2048, 256, 0, stream>>>(p1, p2, rep2, out);
    // PROBE: sim launched twice (idempotent). total - 87.2us baseline
    // = one true sim dispatch + ~2us launch. See header comment.
    sim_kernel<<<dim3(32, 32), 256, 0, stream>>>((const uint4*)rep2, rowsumP, pos);
    sim_kernel<<<dim3(32, 32), 256, 0, stream>>>((const uint4*)rep2, rowsumP, pos);
    fin_kernel<<<64, 128, 0, stream>>>(rowsumP, pos, out);
}

// Round 7
// 84.587 us; speedup vs baseline: 1.3271x; 1.3271x over previous
//
#include <hip/hip_runtime.h>
#include <stdint.h>

typedef __bf16 bf16;
typedef bf16 bf16x8 __attribute__((ext_vector_type(8)));
typedef float floatx4 __attribute__((ext_vector_type(4)));

#define INV_T     2.0f                      // 1 / TEMPERATURE
#define SQRT_K    1.6986436206f             // sqrt(INV_T * log2(e))
#define INV_K     0.34657359028f            // ln(2)/2 = 1/(INV_T*log2(e))
#define GLOBAL_AS __attribute__((address_space(1)))
#define LDS_AS    __attribute__((address_space(3)))

// rep2 layout (16B chunks): chunk(r, ch) = (r>>6)*1024 + ch*64 + (r&63),
// ch = k>>3. MFMA A/B fragment loads and tile staging are fully coalesced,
// LDS fragment reads structurally conflict-free.

// MEASUREMENT LOG:
//  R14 probe (sim launched 2x): sim dispatch = 25.1us delta => ~23us true,
//  vs ~4-6us pipe-work floor. Stall-dominated at 2 waves/SIMD (68KB LDS ->
//  2 blocks/CU, 4-wave blocks). R13 (no staging, direct L2 B reads) was
//  WORSE (+4us): occupancy alone isn't it, the per-wave serial chain with
//  L2-latency loads is. R15: same 256x256 tile + one-shot 64KB stage, but
//  8 WAVES x 32 ROWS (512 thr). Halves per-wave live set (~100 VGPR, fits
//  the 128 cap of launch_bounds(512,4)) and per-wave chain; 4 waves/SIMD.

// ---------------------------------------------------------------------------
// Kernel 1: L2-normalize rows, scale by SQRT_K, write bf16 rep2 (swizzled).
// ---------------------------------------------------------------------------
__global__ __launch_bounds__(256) void nrm_kernel(const float* __restrict__ p1,
                                                  const float* __restrict__ p2,
                                                  uint32_t* __restrict__ rep2,
                                                  float* __restrict__ out) {
    int gt   = blockIdx.x * 256 + threadIdx.x;
    int row  = gt >> 6;
    int lane = gt & 63;
    const float* srcRow = (row < 4096) ? (p1 + (size_t)row * 128)
                                       : (p2 + (size_t)(row - 4096) * 128);
    float2 v = ((const float2*)srcRow)[lane];
    float ss = v.x * v.x + v.y * v.y;
#pragma unroll
    for (int s = 1; s < 64; s <<= 1) ss += __shfl_xor(ss, s, 64);
    float inv = SQRT_K / fmaxf(sqrtf(ss), 1e-12f);
    union { bf16 h[2]; uint32_t u; } pk;
    pk.h[0] = (bf16)(v.x * inv);
    pk.h[1] = (bf16)(v.y * inv);
    int chunk = (row >> 6) * 1024 + (lane >> 2) * 64 + (row & 63);
    rep2[chunk * 4 + (lane & 3)] = pk.u;
    if (gt == 0) *out = 0.0f;
}

// ---------------------------------------------------------------------------
// Kernel 2: SYMMETRIC rowsum partials + positive-pair dot.
// dim3(32,32) grid, upper-triangle blocks only (cb >= rb; lower exits).
// 512 threads = 8 waves; wave w owns 32 rows [rb*256 + w*32, +32).
//   row partials (sum over its 256 cols)  -> rowsumP[row][cb]
//   col partials (sum over its 256 rows)  -> rowsumP[col][rb]   (cb != rb)
// Partner tiles (rb, rb+16) write pos[i] / pos[i+4096] from strip diagonal.
//
// REGISTER-BUDGET HISTORY (don't re-tighten blindly):
//   4-wave blocks: (256,4) cap128 spilled (live ~130). 8-wave blocks halve
//   the live set (aF 32, acc 8, rs 8 => ~100) -> (512,4) cap128 fits.
// ---------------------------------------------------------------------------
__global__ __launch_bounds__(512, 4) void sim_kernel(const uint4* __restrict__ rep2,
                                                     float* __restrict__ rowsumP,
                                                     float* __restrict__ pos) {
    __shared__ uint4 lB[4096];          // 64 KB: full 256-col x 128-k B panel
    __shared__ float colPart[8][256];   // 8 KB cross-wave colsum combine

    const int cb = blockIdx.x;     // col block: cols [cb*256, +256)
    const int rb = blockIdx.y;     // row block: rows [rb*256, +256)
    if (cb < rb) return;           // symmetry: upper triangle only

    const int tid  = threadIdx.x;
    const int w    = tid >> 6;          // wave 0..7
    const int lane = tid & 63;
    const int quad = lane >> 4;
    const int lcol = lane & 15;

    // Stage the WHOLE B panel in one shot: rep2[cb*4096 .. +4096) uint4s.
    // 8 gload_lds x 512 threads = 4096 chunks. LDS dest linear in tid.
    {
        const uint4* src = rep2 + (size_t)cb * 4096;
#pragma unroll
        for (int jj = 0; jj < 8; jj++)
            __builtin_amdgcn_global_load_lds(
                (const GLOBAL_AS uint32_t*)(src + jj * 512 + tid),
                (LDS_AS uint32_t*)&lB[jj * 512 + tid], 16, 0, 0);
    }

    const int wbase = rb * 256 + w * 32;       // wave's rows (32-aligned)
    const int pbase = (wbase + 4096) & 8191;   // partner 32-col window

    // A fragments: rows wbase+mi*16+lcol (mi=0..1), k = ks*32+quad*8..+7.
    // chunk(r,ch) with r = wbase+mi*16+lcol: 64-group = rb*4 + (w>>1),
    // in-group row = (w&1)*32 + mi*16 + lcol.
    bf16x8 aF[2][4];
    const uint4* aG = rep2 + (size_t)(rb * 4 + (w >> 1)) * 1024;
#pragma unroll
    for (int mi = 0; mi < 2; mi++)
#pragma unroll
        for (int ks = 0; ks < 4; ks++)
            aF[mi][ks] = *(const bf16x8*)&aG[(ks * 4 + quad) * 64 + (w & 1) * 32 + mi * 16 + lcol];

    float rs[8];
#pragma unroll
    for (int i = 0; i < 8; i++) rs[i] = 0.0f;

    __syncthreads();   // one drain: panel in LDS, aF in regs

    // 16 subtiles, no barriers anywhere inside.
#pragma unroll
    for (int t = 0; t < 4; t++) {
#pragma unroll
        for (int so = 0; so < 4; so++) {
            bf16x8 bF[4];
#pragma unroll
            for (int ks = 0; ks < 4; ks++)
                bF[ks] = *(const bf16x8*)&lB[t * 1024 + (ks * 4 + quad) * 64 + so * 16 + lcol];

            floatx4 acc[2];
            const floatx4 zf = {0.0f, 0.0f, 0.0f, 0.0f};
#pragma unroll
            for (int mi = 0; mi < 2; mi++) acc[mi] = zf;
#pragma unroll
            for (int ks = 0; ks < 4; ks++)
#pragma unroll
                for (int mi = 0; mi < 2; mi++)
                    acc[mi] = __builtin_amdgcn_mfma_f32_16x16x32_bf16(
                        aF[mi][ks], bF[ks], acc[mi], 0, 0, 0);

            const int c0s  = cb * 256 + t * 64 + so * 16;
            const int gcol = c0s + lcol;
            const bool diagS = ((c0s & ~31) == wbase);   // => rb==cb, diag strip
            const bool partS = ((c0s & ~31) == pbase);   // => cb==rb+16 strip
            float cs = 0.0f;                             // colsum partial
            if (diagS | partS) {
#pragma unroll
                for (int mi = 0; mi < 2; mi++)
#pragma unroll
                    for (int r = 0; r < 4; r++) {
                        int grow = wbase + mi * 16 + quad * 4 + r;
                        float s = acc[mi][r];
                        if (partS && gcol == grow + 4096) {   // rb<16 here
                            float d = s * INV_K;              // raw dot
                            pos[grow] = d;
                            pos[grow + 4096] = d;
                        }
                        float e = __builtin_amdgcn_exp2f(s);
                        if (diagS && grow == gcol) e = 0.0f;  // mask j == i
                        rs[mi * 4 + r] += e;
                        cs += e;
                    }
            } else {
#pragma unroll
                for (int mi = 0; mi < 2; mi++)
#pragma unroll
                    for (int r = 0; r < 4; r++) {
                        float e = __builtin_amdgcn_exp2f(acc[mi][r]);
                        rs[mi * 4 + r] += e;
                        cs += e;
                    }
            }
            // colsum over the wave's 32 rows: reduce across quads
            cs += __shfl_xor(cs, 16, 64);
            cs += __shfl_xor(cs, 32, 64);
            if (quad == 0) colPart[w][t * 64 + so * 16 + lcol] = cs;
        }
    }

    // row partials: reduce rs across lane bits 0-3 (16 cols per quad)
#pragma unroll
    for (int s = 1; s < 16; s <<= 1)
#pragma unroll
        for (int k = 0; k < 8; k++) rs[k] += __shfl_xor(rs[k], s, 64);

    if (lcol == 0) {
#pragma unroll
        for (int k = 0; k < 8; k++) {
            int grow = wbase + (k >> 2) * 16 + quad * 4 + (k & 3);
            rowsumP[(size_t)grow * 32 + cb] = rs[k];   // slot cb
        }
    }

    __syncthreads();   // colPart visibility for the cross-wave combine

    // col partials -> mirror rows' slot rb (skip self-tile)
    if (rb != cb && tid < 256) {
        float c = 0.0f;
#pragma unroll
        for (int ww = 0; ww < 8; ww++) c += colPart[ww][tid];
        rowsumP[(size_t)(cb * 256 + tid) * 32 + rb] = c;
    }
}

// ---------------------------------------------------------------------------
// Kernel 3: loss = (1/8192) * sum_i [ log(sum_c rowsumP[i][c]) - 2*pos_i ]
// ---------------------------------------------------------------------------
__global__ __launch_bounds__(128) void fin_kernel(const float* __restrict__ rowsumP,
                                                  const float* __restrict__ pos,
                                                  float* __restrict__ out) {
    int row = blockIdx.x * 128 + threadIdx.x;
    const floatx4* rp = (const floatx4*)(rowsumP + (size_t)row * 32);
    float d = 0.0f;
#pragma unroll
    for (int j = 0; j < 8; j++) {
        floatx4 q = rp[j];
        d += (q[0] + q[1]) + (q[2] + q[3]);
    }
    float v = logf(d) - pos[row] * INV_T;
#pragma unroll
    for (int s = 1; s < 64; s <<= 1) v += __shfl_xor(v, s, 64);
    __shared__ float red[2];
    if ((threadIdx.x & 63) == 0) red[threadIdx.x >> 6] = v;
    __syncthreads();
    if (threadIdx.x == 0)
        atomicAdd(out, (red[0] + red[1]) * (1.0f / 8192.0f));
}

extern "C" void kernel_launch(void* const* d_in, const int* in_sizes, int n_in,
                              void* d_out, int out_size, void* d_ws, size_t ws_size,
                              hipStream_t stream) {
    const float* p1 = (const float*)d_in[0];
    const float* p2 = (const float*)d_in[1];
    float* out = (float*)d_out;

    char* ws       = (char*)d_ws;
    uint32_t* rep2 = (uint32_t*)ws;                             // 2 MB
    float* rowsumP = (float*)(ws + (2u << 20));                 // 1 MB
    float* pos     = (float*)(ws + (3u << 20));                 // 32 KB

    nrm_kernel<<<2048, 256, 0, stream>>>(p1, p2, rep2, out);
    sim_kernel<<<dim3(32, 32), 512, 0, stream>>>((const uint4*)rep2, rowsumP, pos);
    fin_kernel<<<64, 128, 0, stream>>>(rowsumP, pos, out);
}

// Round 8
// 81.638 us; speedup vs baseline: 1.3750x; 1.0361x over previous
//
#include <hip/hip_runtime.h>
#include <stdint.h>

typedef __bf16 bf16;
typedef bf16 bf16x8 __attribute__((ext_vector_type(8)));
typedef float floatx4 __attribute__((ext_vector_type(4)));

#define INV_T     2.0f                      // 1 / TEMPERATURE
#define SQRT_K    1.6986436206f             // sqrt(INV_T * log2(e))
#define INV_K     0.34657359028f            // ln(2)/2 = 1/(INV_T*log2(e))
#define GLOBAL_AS __attribute__((address_space(1)))
#define LDS_AS    __attribute__((address_space(3)))

// rep2 layout (16B chunks): chunk(r, ch) = (r>>6)*1024 + ch*64 + (r&63),
// ch = k>>3. MFMA A/B fragment loads and tile staging are fully coalesced,
// LDS fragment reads structurally conflict-free.

// MEASUREMENT LOG:
//  R14 probe: sim(256x256, 528 jobs, 2 blk/CU) = ~23us vs ~5-7us floor.
//  R15 (8 waves, 4/SIMD): total 84.6 (-2.6). Partial => per-wave latency
//  was not the main stall.
//  R16 THEORY: generation tail. 528 jobs > 512 co-resident slots => sim
//  runs TWO full generations (block time ~= generation time). Fix: 128x128
//  tiles => 2080 jobs, 34.5KB LDS => 4 blk/CU => 1024 slots, ~2 generations
//  of 4x-shorter blocks + amortized tail. Per-thread live set identical to
//  R15 (~100 VGPR, fits (256,4) cap 128 -- NOT R7's spilling 4x4 layout).

// ---------------------------------------------------------------------------
// Kernel 1: L2-normalize rows, scale by SQRT_K, write bf16 rep2 (swizzled).
// ---------------------------------------------------------------------------
__global__ __launch_bounds__(256) void nrm_kernel(const float* __restrict__ p1,
                                                  const float* __restrict__ p2,
                                                  uint32_t* __restrict__ rep2,
                                                  float* __restrict__ out) {
    int gt   = blockIdx.x * 256 + threadIdx.x;
    int row  = gt >> 6;
    int lane = gt & 63;
    const float* srcRow = (row < 4096) ? (p1 + (size_t)row * 128)
                                       : (p2 + (size_t)(row - 4096) * 128);
    float2 v = ((const float2*)srcRow)[lane];
    float ss = v.x * v.x + v.y * v.y;
#pragma unroll
    for (int s = 1; s < 64; s <<= 1) ss += __shfl_xor(ss, s, 64);
    float inv = SQRT_K / fmaxf(sqrtf(ss), 1e-12f);
    union { bf16 h[2]; uint32_t u; } pk;
    pk.h[0] = (bf16)(v.x * inv);
    pk.h[1] = (bf16)(v.y * inv);
    int chunk = (row >> 6) * 1024 + (lane >> 2) * 64 + (row & 63);
    rep2[chunk * 4 + (lane & 3)] = pk.u;
    if (gt == 0) *out = 0.0f;
}

// ---------------------------------------------------------------------------
// Kernel 2: SYMMETRIC rowsum partials + positive-pair dot. 128x128 tiles.
// Exact 2080-block grid decoded to upper-triangle (rb, cb), cb >= rb,
// rb,cb in [0,64). 256 threads = 4 waves; wave w owns 32 rows.
//   row partials (sum over its 128 cols)  -> rowsumP[row][cb]  (64 slots)
//   col partials (sum over its 128 rows)  -> rowsumP[col][rb]  (cb != rb)
// Partner tiles (cb == rb+32) write pos[i] / pos[i+4096] from the strip
// diagonal. 32KB B panel staged once via global_load_lds, one drain
// barrier, 8 barrier-free subtiles.
// ---------------------------------------------------------------------------
__global__ __launch_bounds__(256, 4) void sim_kernel(const uint4* __restrict__ rep2,
                                                     float* __restrict__ rowsumP,
                                                     float* __restrict__ pos) {
    __shared__ uint4 lB[2048];          // 32 KB: 128-col x 128-k B panel
    __shared__ float colPart[4][128];   // 2 KB cross-wave colsum combine

    // triangular decode: j -> (rb, cb), cb >= rb  (proven in R11/R12 runs)
    const int j  = blockIdx.x;          // 0..2079
    int jpp = 2079 - j;
    int m = (int)((sqrtf((float)(8 * jpp + 1)) - 1.0f) * 0.5f);
    while ((m + 1) * (m + 2) / 2 <= jpp) ++m;   // exact integer fixup
    while (m * (m + 1) / 2 > jpp) --m;
    const int rb = 63 - m;
    const int cb = 63 - (jpp - m * (m + 1) / 2);

    const int tid  = threadIdx.x;
    const int w    = tid >> 6;          // wave 0..3
    const int lane = tid & 63;
    const int quad = lane >> 4;
    const int lcol = lane & 15;

    // Stage the B panel: rep2[cb*2048 .. +2048) uint4s (cols cb*128..+128,
    // all k). 8 gload_lds x 256 threads = 2048 chunks, LDS dest linear.
    {
        const uint4* src = rep2 + (size_t)cb * 2048;
#pragma unroll
        for (int jj = 0; jj < 8; jj++)
            __builtin_amdgcn_global_load_lds(
                (const GLOBAL_AS uint32_t*)(src + jj * 256 + tid),
                (LDS_AS uint32_t*)&lB[jj * 256 + tid], 16, 0, 0);
    }

    const int wbase = rb * 128 + w * 32;       // wave's rows (32-aligned)
    const int pbase = (wbase + 4096) & 8191;   // partner 32-col window

    // A fragments: rows wbase+mi*16+lcol (mi=0..1), k = ks*32+quad*8..+7.
    // 64-group = rb*2 + (w>>1); in-group row = (w&1)*32 + mi*16 + lcol.
    bf16x8 aF[2][4];
    const uint4* aG = rep2 + (size_t)(rb * 2 + (w >> 1)) * 1024;
#pragma unroll
    for (int mi = 0; mi < 2; mi++)
#pragma unroll
        for (int ks = 0; ks < 4; ks++)
            aF[mi][ks] = *(const bf16x8*)&aG[(ks * 4 + quad) * 64 + (w & 1) * 32 + mi * 16 + lcol];

    float rs[8];
#pragma unroll
    for (int i = 0; i < 8; i++) rs[i] = 0.0f;

    __syncthreads();   // one drain: panel in LDS, aF in regs

    // 8 subtiles (t<2 x so<4), no barriers anywhere inside.
#pragma unroll
    for (int t = 0; t < 2; t++) {
#pragma unroll
        for (int so = 0; so < 4; so++) {
            bf16x8 bF[4];
#pragma unroll
            for (int ks = 0; ks < 4; ks++)
                bF[ks] = *(const bf16x8*)&lB[t * 1024 + (ks * 4 + quad) * 64 + so * 16 + lcol];

            floatx4 acc[2];
            const floatx4 zf = {0.0f, 0.0f, 0.0f, 0.0f};
#pragma unroll
            for (int mi = 0; mi < 2; mi++) acc[mi] = zf;
#pragma unroll
            for (int ks = 0; ks < 4; ks++)
#pragma unroll
                for (int mi = 0; mi < 2; mi++)
                    acc[mi] = __builtin_amdgcn_mfma_f32_16x16x32_bf16(
                        aF[mi][ks], bF[ks], acc[mi], 0, 0, 0);

            const int c0s  = cb * 128 + t * 64 + so * 16;
            const int gcol = c0s + lcol;
            const bool diagS = ((c0s & ~31) == wbase);   // => rb==cb diag strip
            const bool partS = ((c0s & ~31) == pbase);   // => cb==rb+32 strip
            float cs = 0.0f;                             // colsum partial
            if (diagS | partS) {
#pragma unroll
                for (int mi = 0; mi < 2; mi++)
#pragma unroll
                    for (int r = 0; r < 4; r++) {
                        int grow = wbase + mi * 16 + quad * 4 + r;
                        float s = acc[mi][r];
                        if (partS && gcol == grow + 4096) {   // rb<32 here
                            float d = s * INV_K;              // raw dot
                            pos[grow] = d;
                            pos[grow + 4096] = d;
                        }
                        float e = __builtin_amdgcn_exp2f(s);
                        if (diagS && grow == gcol) e = 0.0f;  // mask j == i
                        rs[mi * 4 + r] += e;
                        cs += e;
                    }
            } else {
#pragma unroll
                for (int mi = 0; mi < 2; mi++)
#pragma unroll
                    for (int r = 0; r < 4; r++) {
                        float e = __builtin_amdgcn_exp2f(acc[mi][r]);
                        rs[mi * 4 + r] += e;
                        cs += e;
                    }
            }
            // colsum over the wave's 32 rows: reduce across quads
            cs += __shfl_xor(cs, 16, 64);
            cs += __shfl_xor(cs, 32, 64);
            if (quad == 0) colPart[w][t * 64 + so * 16 + lcol] = cs;
        }
    }

    // row partials: reduce rs across lane bits 0-3 (16 cols per quad)
#pragma unroll
    for (int s = 1; s < 16; s <<= 1)
#pragma unroll
        for (int k = 0; k < 8; k++) rs[k] += __shfl_xor(rs[k], s, 64);

    if (lcol == 0) {
#pragma unroll
        for (int k = 0; k < 8; k++) {
            int grow = wbase + (k >> 2) * 16 + quad * 4 + (k & 3);
            rowsumP[(size_t)grow * 64 + cb] = rs[k];   // slot cb (of 64)
        }
    }

    __syncthreads();   // colPart visibility for the cross-wave combine

    // col partials -> mirror rows' slot rb (skip self-tile)
    if (rb != cb && tid < 128) {
        float c = colPart[0][tid] + colPart[1][tid] + colPart[2][tid] + colPart[3][tid];
        rowsumP[(size_t)(cb * 128 + tid) * 64 + rb] = c;
    }
}

// ---------------------------------------------------------------------------
// Kernel 3: loss = (1/8192) * sum_i [ log(sum_c rowsumP[i][c]) - 2*pos_i ]
// ---------------------------------------------------------------------------
__global__ __launch_bounds__(128) void fin_kernel(const float* __restrict__ rowsumP,
                                                  const float* __restrict__ pos,
                                                  float* __restrict__ out) {
    int row = blockIdx.x * 128 + threadIdx.x;
    const floatx4* rp = (const floatx4*)(rowsumP + (size_t)row * 64);
    float d = 0.0f;
#pragma unroll
    for (int j = 0; j < 16; j++) {
        floatx4 q = rp[j];
        d += (q[0] + q[1]) + (q[2] + q[3]);
    }
    float v = logf(d) - pos[row] * INV_T;
#pragma unroll
    for (int s = 1; s < 64; s <<= 1) v += __shfl_xor(v, s, 64);
    __shared__ float red[2];
    if ((threadIdx.x & 63) == 0) red[threadIdx.x >> 6] = v;
    __syncthreads();
    if (threadIdx.x == 0)
        atomicAdd(out, (red[0] + red[1]) * (1.0f / 8192.0f));
}

extern "C" void kernel_launch(void* const* d_in, const int* in_sizes, int n_in,
                              void* d_out, int out_size, void* d_ws, size_t ws_size,
                              hipStream_t stream) {
    const float* p1 = (const float*)d_in[0];
    const float* p2 = (const float*)d_in[1];
    float* out = (float*)d_out;

    char* ws       = (char*)d_ws;
    uint32_t* rep2 = (uint32_t*)ws;                             // 2 MB
    float* rowsumP = (float*)(ws + (2u << 20));                 // 2 MB (64 slots)
    float* pos     = (float*)(ws + (4u << 20));                 // 32 KB

    nrm_kernel<<<2048, 256, 0, stream>>>(p1, p2, rep2, out);
    sim_kernel<<<2080, 256, 0, stream>>>((const uint4*)rep2, rowsumP, pos);
    fin_kernel<<<64, 128, 0, stream>>>(rowsumP, pos, out);
}

// Round 9
// 80.962 us; speedup vs baseline: 1.3865x; 1.0083x over previous
//
#include <hip/hip_runtime.h>
#include <stdint.h>

typedef __bf16 bf16;
typedef bf16 bf16x8 __attribute__((ext_vector_type(8)));
typedef float floatx4 __attribute__((ext_vector_type(4)));

#define INV_T     2.0f                      // 1 / TEMPERATURE
#define SQRT_K    1.6986436206f             // sqrt(INV_T * log2(e))
#define INV_K     0.34657359028f            // ln(2)/2 = 1/(INV_T*log2(e))
#define GLOBAL_AS __attribute__((address_space(1)))
#define LDS_AS    __attribute__((address_space(3)))

// rep2 layout (16B chunks): chunk(r, ch) = (r>>6)*1024 + ch*64 + (r&63),
// ch = k>>3. MFMA A/B fragment loads and tile staging are fully coalesced,
// LDS fragment reads structurally conflict-free.

// MEASUREMENT LOG:
//  R14 probe: sim(256x256, 528 jobs, 2 blk/CU) = ~23us vs ~5-7us floor.
//  R15 (8 waves, 4/SIMD):   84.6 (-2.6)
//  R16 (128x128, 2080 jobs, 4 blk/CU): 81.6 (-3.0). sim LDS-pipe model
//    (~22k cyc/CU: 32 ds_read_b128 + ~48 shfl per wave-job) ~= runtime =>
//    sim near structural floor for the 16x16 fragment layout.
//  R17: (a) nrm grid-stride 2048->512 blocks (dispatch-bound theory: 6MB
//    of traffic needs ~1us of BW, 2048 trivial dispatches cost multi-us);
//    (b) sim split-stage counted-vmcnt (T4): aF issued oldest, stage jj0-3,
//    jj4-7 order-pinned; vmcnt(4)+raw s_barrier opens t=0 while jj4-7 in
//    flight; vmcnt(0)+barrier before t=1. Exact grid => no early-exit =>
//    raw barriers safe.

// ---------------------------------------------------------------------------
// Kernel 1: L2-normalize rows, scale by SQRT_K, write bf16 rep2 (swizzled).
// Grid-stride: 512 blocks x 4 iterations (dispatch-count cut 4x).
// ---------------------------------------------------------------------------
__global__ __launch_bounds__(256) void nrm_kernel(const float* __restrict__ p1,
                                                  const float* __restrict__ p2,
                                                  uint32_t* __restrict__ rep2,
                                                  float* __restrict__ out) {
    if (blockIdx.x == 0 && threadIdx.x == 0) *out = 0.0f;
    const int w    = threadIdx.x >> 6;
    const int lane = threadIdx.x & 63;
#pragma unroll
    for (int it = 0; it < 4; it++) {
        int row = it * 2048 + blockIdx.x * 4 + w;
        const float* srcRow = (row < 4096) ? (p1 + (size_t)row * 128)
                                           : (p2 + (size_t)(row - 4096) * 128);
        float2 v = ((const float2*)srcRow)[lane];
        float ss = v.x * v.x + v.y * v.y;
#pragma unroll
        for (int s = 1; s < 64; s <<= 1) ss += __shfl_xor(ss, s, 64);
        float inv = SQRT_K / fmaxf(sqrtf(ss), 1e-12f);
        union { bf16 h[2]; uint32_t u; } pk;
        pk.h[0] = (bf16)(v.x * inv);
        pk.h[1] = (bf16)(v.y * inv);
        int chunk = (row >> 6) * 1024 + (lane >> 2) * 64 + (row & 63);
        rep2[chunk * 4 + (lane & 3)] = pk.u;
    }
}

// ---------------------------------------------------------------------------
// Kernel 2: SYMMETRIC rowsum partials + positive-pair dot. 128x128 tiles.
// Exact 2080-block grid decoded to upper-triangle (rb, cb), cb >= rb,
// rb,cb in [0,64). 256 threads = 4 waves; wave w owns 32 rows.
//   row partials (sum over its 128 cols)  -> rowsumP[row][cb]  (64 slots)
//   col partials (sum over its 128 rows)  -> rowsumP[col][rb]  (cb != rb)
// Partner tiles (cb == rb+32) write pos[i] / pos[i+4096] from the strip
// diagonal. 32KB B panel staged via global_load_lds in two counted-vmcnt
// halves; t=0 compute overlaps the jj4-7 staging flight.
// ---------------------------------------------------------------------------
__global__ __launch_bounds__(256, 4) void sim_kernel(const uint4* __restrict__ rep2,
                                                     float* __restrict__ rowsumP,
                                                     float* __restrict__ pos) {
    __shared__ uint4 lB[2048];          // 32 KB: 128-col x 128-k B panel
    __shared__ float colPart[4][128];   // 2 KB cross-wave colsum combine

    // triangular decode: j -> (rb, cb), cb >= rb  (proven R11/R12/R16)
    const int j  = blockIdx.x;          // 0..2079
    int jpp = 2079 - j;
    int m = (int)((sqrtf((float)(8 * jpp + 1)) - 1.0f) * 0.5f);
    while ((m + 1) * (m + 2) / 2 <= jpp) ++m;   // exact integer fixup
    while (m * (m + 1) / 2 > jpp) --m;
    const int rb = 63 - m;
    const int cb = 63 - (jpp - m * (m + 1) / 2);

    const int tid  = threadIdx.x;
    const int w    = tid >> 6;          // wave 0..3
    const int lane = tid & 63;
    const int quad = lane >> 4;
    const int lcol = lane & 15;

    const int wbase = rb * 128 + w * 32;       // wave's rows (32-aligned)
    const int pbase = (wbase + 4096) & 8191;   // partner 32-col window

    // A fragments FIRST (oldest VMEM, so vmcnt(4) below covers them).
    // rows wbase+mi*16+lcol (mi=0..1), k = ks*32+quad*8..+7.
    bf16x8 aF[2][4];
    const uint4* aG = rep2 + (size_t)(rb * 2 + (w >> 1)) * 1024;
#pragma unroll
    for (int mi = 0; mi < 2; mi++)
#pragma unroll
        for (int ks = 0; ks < 4; ks++)
            aF[mi][ks] = *(const bf16x8*)&aG[(ks * 4 + quad) * 64 + (w & 1) * 32 + mi * 16 + lcol];
    __builtin_amdgcn_sched_barrier(0);   // pin: aF issue before stage issue

    // Stage B panel halves: jj0-3 feed t=0 (lB[0..1024)), jj4-7 feed t=1.
    const uint4* src = rep2 + (size_t)cb * 2048;
#pragma unroll
    for (int jj = 0; jj < 4; jj++)
        __builtin_amdgcn_global_load_lds(
            (const GLOBAL_AS uint32_t*)(src + jj * 256 + tid),
            (LDS_AS uint32_t*)&lB[jj * 256 + tid], 16, 0, 0);
    __builtin_amdgcn_sched_barrier(0);   // pin: jj0-3 before jj4-7
#pragma unroll
    for (int jj = 4; jj < 8; jj++)
        __builtin_amdgcn_global_load_lds(
            (const GLOBAL_AS uint32_t*)(src + jj * 256 + tid),
            (LDS_AS uint32_t*)&lB[jj * 256 + tid], 16, 0, 0);
    __builtin_amdgcn_sched_barrier(0);   // youngest-4 VMEM == jj4-7

    float rs[8];
#pragma unroll
    for (int i = 0; i < 8; i++) rs[i] = 0.0f;

    auto subtile_pass = [&](int t) {
#pragma unroll
        for (int so = 0; so < 4; so++) {
            bf16x8 bF[4];
#pragma unroll
            for (int ks = 0; ks < 4; ks++)
                bF[ks] = *(const bf16x8*)&lB[t * 1024 + (ks * 4 + quad) * 64 + so * 16 + lcol];

            floatx4 acc[2];
            const floatx4 zf = {0.0f, 0.0f, 0.0f, 0.0f};
#pragma unroll
            for (int mi = 0; mi < 2; mi++) acc[mi] = zf;
#pragma unroll
            for (int ks = 0; ks < 4; ks++)
#pragma unroll
                for (int mi = 0; mi < 2; mi++)
                    acc[mi] = __builtin_amdgcn_mfma_f32_16x16x32_bf16(
                        aF[mi][ks], bF[ks], acc[mi], 0, 0, 0);

            const int c0s  = cb * 128 + t * 64 + so * 16;
            const int gcol = c0s + lcol;
            const bool diagS = ((c0s & ~31) == wbase);   // => rb==cb diag strip
            const bool partS = ((c0s & ~31) == pbase);   // => cb==rb+32 strip
            float cs = 0.0f;                             // colsum partial
            if (diagS | partS) {
#pragma unroll
                for (int mi = 0; mi < 2; mi++)
#pragma unroll
                    for (int r = 0; r < 4; r++) {
                        int grow = wbase + mi * 16 + quad * 4 + r;
                        float s = acc[mi][r];
                        if (partS && gcol == grow + 4096) {   // rb<32 here
                            float d = s * INV_K;              // raw dot
                            pos[grow] = d;
                            pos[grow + 4096] = d;
                        }
                        float e = __builtin_amdgcn_exp2f(s);
                        if (diagS && grow == gcol) e = 0.0f;  // mask j == i
                        rs[mi * 4 + r] += e;
                        cs += e;
                    }
            } else {
#pragma unroll
                for (int mi = 0; mi < 2; mi++)
#pragma unroll
                    for (int r = 0; r < 4; r++) {
                        float e = __builtin_amdgcn_exp2f(acc[mi][r]);
                        rs[mi * 4 + r] += e;
                        cs += e;
                    }
            }
            // colsum over the wave's 32 rows: reduce across quads
            cs += __shfl_xor(cs, 16, 64);
            cs += __shfl_xor(cs, 32, 64);
            if (quad == 0) colPart[w][t * 64 + so * 16 + lcol] = cs;
        }
    };

    // Phase 0: need my aF + everyone's jj0-3 => vmcnt(4) (jj4-7 youngest).
    asm volatile("s_waitcnt vmcnt(4)" ::: "memory");
    __builtin_amdgcn_s_barrier();
    __builtin_amdgcn_sched_barrier(0);
    subtile_pass(0);

    // Phase 1: everyone's jj4-7 landed.
    asm volatile("s_waitcnt vmcnt(0)" ::: "memory");
    __builtin_amdgcn_s_barrier();
    __builtin_amdgcn_sched_barrier(0);
    subtile_pass(1);

    // row partials: reduce rs across lane bits 0-3 (16 cols per quad)
#pragma unroll
    for (int s = 1; s < 16; s <<= 1)
#pragma unroll
        for (int k = 0; k < 8; k++) rs[k] += __shfl_xor(rs[k], s, 64);

    if (lcol == 0) {
#pragma unroll
        for (int k = 0; k < 8; k++) {
            int grow = wbase + (k >> 2) * 16 + quad * 4 + (k & 3);
            rowsumP[(size_t)grow * 64 + cb] = rs[k];   // slot cb (of 64)
        }
    }

    __syncthreads();   // colPart visibility for the cross-wave combine

    // col partials -> mirror rows' slot rb (skip self-tile)
    if (rb != cb && tid < 128) {
        float c = colPart[0][tid] + colPart[1][tid] + colPart[2][tid] + colPart[3][tid];
        rowsumP[(size_t)(cb * 128 + tid) * 64 + rb] = c;
    }
}

// ---------------------------------------------------------------------------
// Kernel 3: loss = (1/8192) * sum_i [ log(sum_c rowsumP[i][c]) - 2*pos_i ]
// ---------------------------------------------------------------------------
__global__ __launch_bounds__(128) void fin_kernel(const float* __restrict__ rowsumP,
                                                  const float* __restrict__ pos,
                                                  float* __restrict__ out) {
    int row = blockIdx.x * 128 + threadIdx.x;
    const floatx4* rp = (const floatx4*)(rowsumP + (size_t)row * 64);
    float d = 0.0f;
#pragma unroll
    for (int j = 0; j < 16; j++) {
        floatx4 q = rp[j];
        d += (q[0] + q[1]) + (q[2] + q[3]);
    }
    float v = logf(d) - pos[row] * INV_T;
#pragma unroll
    for (int s = 1; s < 64; s <<= 1) v += __shfl_xor(v, s, 64);
    __shared__ float red[2];
    if ((threadIdx.x & 63) == 0) red[threadIdx.x >> 6] = v;
    __syncthreads();
    if (threadIdx.x == 0)
        atomicAdd(out, (red[0] + red[1]) * (1.0f / 8192.0f));
}

extern "C" void kernel_launch(void* const* d_in, const int* in_sizes, int n_in,
                              void* d_out, int out_size, void* d_ws, size_t ws_size,
                              hipStream_t stream) {
    const float* p1 = (const float*)d_in[0];
    const float* p2 = (const float*)d_in[1];
    float* out = (float*)d_out;

    char* ws       = (char*)d_ws;
    uint32_t* rep2 = (uint32_t*)ws;                             // 2 MB
    float* rowsumP = (float*)(ws + (2u << 20));                 // 2 MB (64 slots)
    float* pos     = (float*)(ws + (4u << 20));                 // 32 KB

    nrm_kernel<<<512, 256, 0, stream>>>(p1, p2, rep2, out);
    sim_kernel<<<2080, 256, 0, stream>>>((const uint4*)rep2, rowsumP, pos);
    fin_kernel<<<64, 128, 0, stream>>>(rowsumP, pos, out);
}